// Round 12
// baseline (77.594 us; speedup 1.0000x reference)
//
#include <hip/hip_runtime.h>
#include <hip/hip_bf16.h>

#define BATCH 4
#define NPTS 8192
#define TPB 256
#define RSPLIT 8                    // row-split partial-min slices (no atomics)
#define CGROUPS 16                  // colgroups per side (512 cols each)
#define TOTAL (2 * BATCH * NPTS)    // 65536 output slots
#define GRID (8 * CGROUPS * RSPLIT) // 1024 blocks, 4/CU

typedef short bf16x8 __attribute__((ext_vector_type(8)));
typedef float f32x16 __attribute__((ext_vector_type(16)));

__device__ __forceinline__ unsigned short b16(float f) {   // fp32 -> bf16 RNE (HW cvt)
  __hip_bfloat16 h = __float2bfloat16(f);
  return __builtin_bit_cast(unsigned short, h);
}
__device__ __forceinline__ float b2f(unsigned short h) {
  return __uint_as_float(((unsigned)h) << 16);
}

// MFMA with destination FORCED into ArchVGPRs ("v" constraint; "a" would be
// AGPR). Eliminates the suspected 16x v_accvgpr_read/MFMA consumption tax
// (R19: consumption ~3x its nominal issue cost; R16: VALU-issue saturated).
// R21 LESSON: hipcc's hazard recognizer does NOT protect reads of asm MFMA
// results -> we close the MFMA-dest->VALU-read hazard OURSELVES with 24
// embedded wait cycles (> ~18 required for 16-pass MFMA). s_nop is per-wave
// and covered by the other 3 waves/SIMD. C-operand is a loop-invariant zero
// tuple in VGPRs (materialized once outside the loop). Early-clobber dest
// so it never aliases A/B/C.
__device__ __forceinline__ f32x16 mfma_vgpr(bf16x8 a, bf16x8 b, f32x16 z) {
  f32x16 d;
  asm volatile("v_mfma_f32_32x32x16_bf16 %0, %1, %2, %3\n\t"
               "s_nop 7\n\t"
               "s_nop 7\n\t"
               "s_nop 7"
               : "=&v"(d)
               : "v"(a), "v"(b), "v"(z));
  return d;
}

// K=16 packed rows (R8/R10/R11-verified exact, absmax 0.0):
//  roleA(x): [(-2x)h(3), (-2x)l(3), (-2x)h(3), x2h, x2l, 1,   1,  0,0,0]
//  roleB(y): [yh(3),     yh(3),     yl(3),     1,   1, y2h, y2l, 0,0,0]
// roleA.roleB = squared distance minus (-2x)l.yl (~1e-5 << 9.3e-4 threshold).
__device__ __forceinline__ void pack_halves(uint4* lo, uint4* hi, float cx,
                                            float cy, float cz, bool roleA) {
  float n2 = cx * cx + cy * cy + cz * cz;
  float vx = roleA ? -2.f * cx : cx;
  float vy = roleA ? -2.f * cy : cy;
  float vz = roleA ? -2.f * cz : cz;
  unsigned hx = b16(vx), hy = b16(vy), hz = b16(vz);
  unsigned lx = b16(vx - b2f(hx)), ly = b16(vy - b2f(hy)), lz = b16(vz - b2f(hz));
  unsigned nh = b16(n2), nl = b16(n2 - b2f(nh));
  const unsigned ONE = 0x3F80u;
  if (roleA) {
    *lo = make_uint4(hx | (hy << 16), hz | (lx << 16), ly | (lz << 16), hx | (hy << 16));
    *hi = make_uint4(hz | (nh << 16), nl | (ONE << 16), ONE, 0u);
  } else {
    *lo = make_uint4(hx | (hy << 16), hz | (hx << 16), hy | (hz << 16), lx | (ly << 16));
    *hi = make_uint4(lz | (ONE << 16), ONE | (nh << 16), nl, 0u);
  }
}

// R23 — R15/R22 proven structure + VGPR-dest MFMA (see mfma_vgpr above).
// Everything else R15-verified: lane-ordered LDS units ((p>>5)*64+(p&31),
// hi +32; writer/reader lane-stride-1, 0 conflicts measured), in-register
// col pack (lane<32 lo else hi), in-lane row-min (C/D: col=lane&31,
// row=(reg&3)+8*(reg>>2)+4*(lane>>5)), fminf depth-3 tree (fuses to
// v_min3; R14-R22 bit-identical), shfl_xor(32) merge, coalesced partial
// stores, separate reduce kernel.
__global__ __launch_bounds__(TPB, 4) void chamfer_nn(
    const float* __restrict__ pred, const float* __restrict__ gt,
    float* __restrict__ partial, float* __restrict__ out) {
  __shared__ __align__(16) unsigned short sB[1024 * 16];   // 32 KB row frags

  int blk = blockIdx.x;
  int rq   = blk & (RSPLIT - 1);         // row slice (1024 rows = 32 tiles)
  int cg   = (blk >> 3) & (CGROUPS - 1); // colgroup (512 cols = 16 tiles)
  int side = blk >> 7;                   // dir*4 + b
  int dir = side >> 2, b = side & 3;

  const float* As = (dir ? gt : pred) + (size_t)b * NPTS * 3;  // cols (outputs)
  const float* Bs = (dir ? pred : gt) + (size_t)b * NPTS * 3;  // rows (min'ed)

  int t = threadIdx.x, w = t >> 6, lane = t & 63;
  if (blk == 0 && t == 0) out[0] = 0.f;   // zero accumulator for reduce pass

  int rowbase = rq * 1024;

  // ---- Stage rows: 4 points/thread into lane-ordered LDS units. ----
  #pragma unroll
  for (int h = 0; h < 4; ++h) {
    int p = h * 256 + t;                 // local row 0..1023
    int gp = rowbase + p;
    uint4 lo, hi;
    pack_halves(&lo, &hi, Bs[gp * 3], Bs[gp * 3 + 1], Bs[gp * 3 + 2], true);
    unsigned short* u0 = sB + ((p >> 5) * 64 + (p & 31)) * 8;
    *(uint4*)u0 = lo;
    *(uint4*)(u0 + 32 * 8) = hi;
  }

  // ---- Col operands in-register: wave w owns col tiles cg*16+w*4+{0..3}.
  bf16x8 af[4];
  #pragma unroll
  for (int j = 0; j < 4; ++j) {
    int gp = (cg * 16 + w * 4 + j) * 32 + (lane & 31);
    uint4 lo, hi;
    pack_halves(&lo, &hi, As[gp * 3], As[gp * 3 + 1], As[gp * 3 + 2], false);
    uint4 sel = (lane < 32) ? lo : hi;
    af[j] = __builtin_bit_cast(bf16x8, sel);
  }

  __syncthreads();   // single barrier: rows staged

  const f32x16 Z = {0.f,0.f,0.f,0.f,0.f,0.f,0.f,0.f,0.f,0.f,0.f,0.f,0.f,0.f,0.f,0.f};
  float m[4] = {3.4e38f, 3.4e38f, 3.4e38f, 3.4e38f};

  #pragma unroll 2
  for (int rt = 0; rt < 32; ++rt) {
    bf16x8 bf = *(const bf16x8*)(sB + (rt * 64 + lane) * 8);
    #pragma unroll
    for (int j = 0; j < 4; ++j) {
      f32x16 d = mfma_vgpr(bf, af[j], Z);
      // Proven fminf tree (fuses to v_min3; R14-R22 bit-identical).
      float t0 = fminf(fminf(d[0], d[1]), d[2]);
      float t1 = fminf(fminf(d[3], d[4]), d[5]);
      float t2 = fminf(fminf(d[6], d[7]), d[8]);
      float t3 = fminf(fminf(d[9], d[10]), d[11]);
      float t4 = fminf(fminf(d[12], d[13]), d[14]);
      float u0 = fminf(fminf(t0, t1), d[15]);
      float u1 = fminf(fminf(t2, t3), t4);
      m[j] = fminf(fminf(m[j], u0), u1);
    }
  }

  #pragma unroll
  for (int j = 0; j < 4; ++j)
    m[j] = fminf(m[j], __shfl_xor(m[j], 32, 64));  // merge row halves
  if (lane < 32) {
    float* dst = partial + (size_t)rq * TOTAL + (size_t)side * NPTS;
    #pragma unroll
    for (int j = 0; j < 4; ++j)
      dst[(cg * 16 + w * 4 + j) * 32 + lane] = fmaxf(m[j], 0.f);
  }
}

// Reduce: min over RSPLIT partials per slot, block-sum, one atomicAdd/block.
// out[0] was zeroed by chamfer_nn (stream-ordered before this kernel).
__global__ __launch_bounds__(TPB) void chamfer_reduce(
    const float* __restrict__ partial, float* __restrict__ out) {
  int t = threadIdx.x;
  int s = blockIdx.x * TPB + t;       // slot 0..65535
  float v = partial[s];
  #pragma unroll
  for (int r = 1; r < RSPLIT; ++r)
    v = fminf(v, partial[(size_t)r * TOTAL + s]);
  #pragma unroll
  for (int off = 32; off > 0; off >>= 1) v += __shfl_down(v, off, 64);
  __shared__ float wsum[4];
  int wave = t >> 6, lane = t & 63;
  if (lane == 0) wsum[wave] = v;
  __syncthreads();
  if (t == 0) {
    float tot = (wsum[0] + wsum[1]) + (wsum[2] + wsum[3]);
    atomicAdd(out, tot * (1.f / (float)(BATCH * NPTS)));
  }
}

extern "C" void kernel_launch(void* const* d_in, const int* in_sizes, int n_in,
                              void* d_out, int out_size, void* d_ws, size_t ws_size,
                              hipStream_t stream) {
  const float* pred = (const float*)d_in[0];
  const float* gt   = (const float*)d_in[1];
  float* out        = (float*)d_out;
  float* partial    = (float*)d_ws;   // RSPLIT x 65536 floats = 2 MB

  chamfer_nn<<<dim3(GRID), dim3(TPB), 0, stream>>>(pred, gt, partial, out);
  chamfer_reduce<<<dim3(TOTAL / TPB), dim3(TPB), 0, stream>>>(partial, out);
}